// Round 1
// baseline (186.802 us; speedup 1.0000x reference)
//
#include <hip/hip_runtime.h>

// Problem constants (from reference): N=8, H=512, W=512, K=1, NF=100000, D=8
#define NN 8
#define HH 512
#define WW 512
#define DD 8

constexpr int HW   = HH * WW;        // 262144 pixels per image (pow2 -> div/mod are shifts)
constexpr int NPIX = NN * HW;        // 2,097,152 total pixels

__global__ __launch_bounds__(256) void interp_face_attrs(
    const int*   __restrict__ p2f,   // [N*H*W] packed face index, -1 = empty
    const float* __restrict__ bary,  // [N*H*W, 3]
    const float* __restrict__ attr,  // [N*NF, 3, D] packed -> 24 floats per face
    float*       __restrict__ out)   // [N, D+1, H, W]
{
    int i = blockIdx.x * blockDim.x + threadIdx.x;
    if (i >= NPIX) return;

    int f = p2f[i];
    int n = i >> 18;            // i / HW
    int p = i & (HW - 1);       // i % HW

    float* ob = out + (size_t)n * (DD + 1) * HW + p;

    if (f < 0) {
        // empty pixel: zero all D channels + vis mask
        #pragma unroll
        for (int d = 0; d < DD + 1; ++d)
            ob[(size_t)d * HW] = 0.0f;
        return;
    }

    // barycentric weights
    size_t bi = (size_t)i * 3;
    float b0 = bary[bi + 0];
    float b1 = bary[bi + 1];
    float b2 = bary[bi + 2];

    // gather 3 vertices x 8 channels = 24 floats = 6 aligned float4s
    const float4* a = (const float4*)(attr + (size_t)f * 24);
    float4 v00 = a[0];  // vert0 ch0-3
    float4 v01 = a[1];  // vert0 ch4-7
    float4 v10 = a[2];
    float4 v11 = a[3];
    float4 v20 = a[4];
    float4 v21 = a[5];

    float o0 = b0 * v00.x + b1 * v10.x + b2 * v20.x;
    float o1 = b0 * v00.y + b1 * v10.y + b2 * v20.y;
    float o2 = b0 * v00.z + b1 * v10.z + b2 * v20.z;
    float o3 = b0 * v00.w + b1 * v10.w + b2 * v20.w;
    float o4 = b0 * v01.x + b1 * v11.x + b2 * v21.x;
    float o5 = b0 * v01.y + b1 * v11.y + b2 * v21.y;
    float o6 = b0 * v01.z + b1 * v11.z + b2 * v21.z;
    float o7 = b0 * v01.w + b1 * v11.w + b2 * v21.w;

    ob[0 * (size_t)HW] = o0;
    ob[1 * (size_t)HW] = o1;
    ob[2 * (size_t)HW] = o2;
    ob[3 * (size_t)HW] = o3;
    ob[4 * (size_t)HW] = o4;
    ob[5 * (size_t)HW] = o5;
    ob[6 * (size_t)HW] = o6;
    ob[7 * (size_t)HW] = o7;
    ob[8 * (size_t)HW] = 1.0f;   // vis mask
}

extern "C" void kernel_launch(void* const* d_in, const int* in_sizes, int n_in,
                              void* d_out, int out_size, void* d_ws, size_t ws_size,
                              hipStream_t stream) {
    const int*   p2f  = (const int*)d_in[0];
    const float* bary = (const float*)d_in[1];
    const float* attr = (const float*)d_in[2];
    float*       out  = (float*)d_out;

    const int block = 256;
    const int grid  = (NPIX + block - 1) / block;
    interp_face_attrs<<<grid, block, 0, stream>>>(p2f, bary, attr, out);
}

// Round 3
// 185.792 us; speedup vs baseline: 1.0054x; 1.0054x over previous
//
#include <hip/hip_runtime.h>

// Problem constants (from reference): N=8, H=512, W=512, K=1, NF=100000, D=8
#define NN 8
#define HH 512
#define WW 512
#define DD 8

constexpr int HW    = HH * WW;       // 262144 pixels per image (pow2)
constexpr int NPIX  = NN * HW;       // 2,097,152 total pixels
constexpr int NPAIR = NPIX / 2;      // 2 pixels per thread

// native clang vector types (nontemporal builtins reject HIP's struct vectors)
typedef float v2f __attribute__((ext_vector_type(2)));
typedef int   v2i __attribute__((ext_vector_type(2)));

__global__ __launch_bounds__(256) void interp_face_attrs2(
    const int*   __restrict__ p2f,   // [N*H*W] packed face index, -1 = empty
    const float* __restrict__ bary,  // [N*H*W, 3]
    const float* __restrict__ attr,  // [N*NF, 3, D] packed -> 24 floats per face
    float*       __restrict__ out)   // [N, D+1, H, W]
{
    int t = blockIdx.x * blockDim.x + threadIdx.x;
    if (t >= NPAIR) return;
    int i0 = t << 1;                 // first pixel of the pair (even)

    // --- streamed inputs (nontemporal: don't pollute L2, attr needs it) ---
    v2i ff = __builtin_nontemporal_load((const v2i*)p2f + t);

    const v2f* bp = (const v2f*)(bary + 6 * (size_t)t);  // 24 B, 8-aligned
    v2f ba = __builtin_nontemporal_load(bp + 0);
    v2f bb = __builtin_nontemporal_load(bp + 1);
    v2f bc = __builtin_nontemporal_load(bp + 2);

    // branchless invalid handling: clamp index to 0, zero the weights
    bool v0 = ff.x >= 0;
    bool v1 = ff.y >= 0;
    int  f0 = v0 ? ff.x : 0;
    int  f1 = v1 ? ff.y : 0;
    float p0b0 = v0 ? ba.x : 0.0f, p0b1 = v0 ? ba.y : 0.0f, p0b2 = v0 ? bb.x : 0.0f;
    float p1b0 = v1 ? bb.y : 0.0f, p1b1 = v1 ? bc.x : 0.0f, p1b2 = v1 ? bc.y : 0.0f;

    // --- random gather: 2 faces x 6 float4 = 12 outstanding 16 B loads ---
    const float4* a0 = (const float4*)(attr + 24 * (size_t)f0);
    const float4* a1 = (const float4*)(attr + 24 * (size_t)f1);
    float4 x00 = a0[0], x01 = a0[1];   // face0 vert0 ch0-7
    float4 x10 = a0[2], x11 = a0[3];   // face0 vert1
    float4 x20 = a0[4], x21 = a0[5];   // face0 vert2
    float4 y00 = a1[0], y01 = a1[1];   // face1 vert0
    float4 y10 = a1[2], y11 = a1[3];
    float4 y20 = a1[4], y21 = a1[5];

    float o0[8], o1[8];
    o0[0] = p0b0 * x00.x + p0b1 * x10.x + p0b2 * x20.x;
    o0[1] = p0b0 * x00.y + p0b1 * x10.y + p0b2 * x20.y;
    o0[2] = p0b0 * x00.z + p0b1 * x10.z + p0b2 * x20.z;
    o0[3] = p0b0 * x00.w + p0b1 * x10.w + p0b2 * x20.w;
    o0[4] = p0b0 * x01.x + p0b1 * x11.x + p0b2 * x21.x;
    o0[5] = p0b0 * x01.y + p0b1 * x11.y + p0b2 * x21.y;
    o0[6] = p0b0 * x01.z + p0b1 * x11.z + p0b2 * x21.z;
    o0[7] = p0b0 * x01.w + p0b1 * x11.w + p0b2 * x21.w;

    o1[0] = p1b0 * y00.x + p1b1 * y10.x + p1b2 * y20.x;
    o1[1] = p1b0 * y00.y + p1b1 * y10.y + p1b2 * y20.y;
    o1[2] = p1b0 * y00.z + p1b1 * y10.z + p1b2 * y20.z;
    o1[3] = p1b0 * y00.w + p1b1 * y10.w + p1b2 * y20.w;
    o1[4] = p1b0 * y01.x + p1b1 * y11.x + p1b2 * y21.x;
    o1[5] = p1b0 * y01.y + p1b1 * y11.y + p1b2 * y21.y;
    o1[6] = p1b0 * y01.z + p1b1 * y11.z + p1b2 * y21.z;
    o1[7] = p1b0 * y01.w + p1b1 * y11.w + p1b2 * y21.w;

    // --- planar output: 9 channels x float2 (pair of adjacent pixels) ---
    int n = i0 >> 18;            // i0 / HW
    int p = i0 & (HW - 1);       // i0 % HW (even -> 8B aligned)
    float* ob = out + (size_t)n * (DD + 1) * HW + p;

    #pragma unroll
    for (int d = 0; d < DD; ++d) {
        v2f v = { o0[d], o1[d] };
        __builtin_nontemporal_store(v, (v2f*)(ob + (size_t)d * HW));
    }
    v2f vis = { v0 ? 1.0f : 0.0f, v1 ? 1.0f : 0.0f };
    __builtin_nontemporal_store(vis, (v2f*)(ob + (size_t)DD * HW));
}

extern "C" void kernel_launch(void* const* d_in, const int* in_sizes, int n_in,
                              void* d_out, int out_size, void* d_ws, size_t ws_size,
                              hipStream_t stream) {
    const int*   p2f  = (const int*)d_in[0];
    const float* bary = (const float*)d_in[1];
    const float* attr = (const float*)d_in[2];
    float*       out  = (float*)d_out;

    const int block = 256;
    const int grid  = (NPAIR + block - 1) / block;
    interp_face_attrs2<<<grid, block, 0, stream>>>(p2f, bary, attr, out);
}

// Round 4
// 182.072 us; speedup vs baseline: 1.0260x; 1.0204x over previous
//
#include <hip/hip_runtime.h>

// Problem constants (from reference): N=8, H=512, W=512, K=1, NF=100000, D=8
#define NN 8
#define HH 512
#define WW 512
#define DD 8

constexpr int HW   = HH * WW;        // 262144 (pow2)
constexpr int NPIX = NN * HW;        // 2,097,152
constexpr int PPB  = 256;            // pixels per block (= block size)
constexpr int CST  = PPB + 4;        // padded pixel-stride for chunk LDS (bank spread)

typedef float v4f __attribute__((ext_vector_type(4)));

// Each face row in attr is 24 floats = 96 B = 6 x float4 "chunks":
//   c0 = vert0 ch0-3, c1 = vert0 ch4-7, c2 = vert1 lo, c3 = vert1 hi, c4 = vert2 lo, c5 = vert2 hi
// Gather phase distributes work-items w = p*6+c over lanes so consecutive lanes
// load consecutive chunks of the SAME face -> VMEM coalescer merges them into
// ~1.5 line-requests/face instead of 6 (L2 request-rate was the bottleneck).
__global__ __launch_bounds__(256) void interp_coop(
    const int*   __restrict__ p2f,   // [N*H*W] packed face index, -1 = empty
    const float* __restrict__ bary,  // [N*H*W, 3]
    const float* __restrict__ attr,  // [N*NF, 3, D] -> 6 float4 per face
    float*       __restrict__ out)   // [N, D+1, H, W]
{
    __shared__ int fIdx[PPB];
    __shared__ v4f chunks[6 * CST];

    const int t = threadIdx.x;
    const int i = blockIdx.x * PPB + t;   // this thread's pixel

    // --- per-pixel stream loads ---
    int f = p2f[i];
    bool valid = f >= 0;
    fIdx[t] = valid ? f : 0;

    size_t bi = (size_t)i * 3;
    float b0 = bary[bi + 0];
    float b1 = bary[bi + 1];
    float b2 = bary[bi + 2];
    if (!valid) { b0 = 0.0f; b1 = 0.0f; b2 = 0.0f; }

    __syncthreads();

    // --- cooperative coalesced gather: 1536 chunk-loads spread over 6 rounds ---
    const v4f* ap = (const v4f*)attr;
    #pragma unroll
    for (int j = 0; j < 6; ++j) {
        int w = j * PPB + t;          // consecutive lanes -> consecutive (p,c)
        int p = w / 6;                // pixel within block
        int c = w - p * 6;            // chunk within face
        int ff = fIdx[p];
        chunks[c * CST + p] = ap[(size_t)ff * 6 + c];
    }

    __syncthreads();

    // --- blend (phase-2 LDS reads: consecutive lanes, conflict-free) ---
    v4f x0 = chunks[0 * CST + t];     // vert0 ch0-3
    v4f x1 = chunks[1 * CST + t];     // vert0 ch4-7
    v4f y0 = chunks[2 * CST + t];
    v4f y1 = chunks[3 * CST + t];
    v4f z0 = chunks[4 * CST + t];
    v4f z1 = chunks[5 * CST + t];

    v4f lo = b0 * x0 + b1 * y0 + b2 * z0;   // ch0-3
    v4f hi = b0 * x1 + b1 * y1 + b2 * z1;   // ch4-7

    // --- planar output [N, D+1, H, W], coalesced per plane ---
    int n = i >> 18;                  // i / HW
    int p = i & (HW - 1);             // i % HW
    float* ob = out + (size_t)n * (DD + 1) * HW + p;

    __builtin_nontemporal_store(lo.x, ob + 0 * (size_t)HW);
    __builtin_nontemporal_store(lo.y, ob + 1 * (size_t)HW);
    __builtin_nontemporal_store(lo.z, ob + 2 * (size_t)HW);
    __builtin_nontemporal_store(lo.w, ob + 3 * (size_t)HW);
    __builtin_nontemporal_store(hi.x, ob + 4 * (size_t)HW);
    __builtin_nontemporal_store(hi.y, ob + 5 * (size_t)HW);
    __builtin_nontemporal_store(hi.z, ob + 6 * (size_t)HW);
    __builtin_nontemporal_store(hi.w, ob + 7 * (size_t)HW);
    __builtin_nontemporal_store(valid ? 1.0f : 0.0f, ob + 8 * (size_t)HW);
}

extern "C" void kernel_launch(void* const* d_in, const int* in_sizes, int n_in,
                              void* d_out, int out_size, void* d_ws, size_t ws_size,
                              hipStream_t stream) {
    const int*   p2f  = (const int*)d_in[0];
    const float* bary = (const float*)d_in[1];
    const float* attr = (const float*)d_in[2];
    float*       out  = (float*)d_out;

    const int grid = NPIX / PPB;      // 8192 blocks
    interp_coop<<<grid, PPB, 0, stream>>>(p2f, bary, attr, out);
}